// Round 4
// baseline (137.420 us; speedup 1.0000x reference)
//
#include <hip/hip_runtime.h>

// DisplaceChannel: out[b,p,c,h,w] = in[b,p,c, h-off_y[p], w-off_x[p]] (0 if OOB)
// B=16, P=9, C/P=32 (C=288), H=W=64. Offsets are multiples of 32 -> 16B
// vectors stay aligned; validity is uniform within each vector.
//
// Traffic floor: write 75.5 MB (all) + read 33.5 MB (valid 4/9) ~= 109 MB
// -> ~17 us at 6.3 TB/s. This version: 2 planes per block (same offset
// group since plane index is even), 256 thr x 8 vectors, all 8 loads in
// flight before the stores (2x MLP vs previous round).

#define B_   16
#define C_   288
#define H_   64
#define W_   64

typedef float f32x4 __attribute__((ext_vector_type(4)));

__global__ __launch_bounds__(256) void displace_kernel(
    const float* __restrict__ inp,
    const int*   __restrict__ offs,
    float*       __restrict__ out)
{
    const int blk    = blockIdx.x;          // [0, B_*C_/2) -- two planes each
    const int plane0 = blk * 2;             // even -> both planes same p-group
    const int c      = plane0 % C_;
    const int p      = c >> 5;              // CHAN_PER_POS = 32
    const int off_x  = offs[2 * p];
    const int off_y  = offs[2 * p + 1];

    const f32x4* __restrict__ src = (const f32x4*)(inp + (size_t)plane0 * (H_ * W_));
    f32x4* __restrict__ dst       = (f32x4*)(out + (size_t)plane0 * (H_ * W_));

    // 2 planes = 2048 vectors; 256 threads x 8 vectors.
    f32x4 r[8];
    #pragma unroll
    for (int k = 0; k < 8; ++k) {
        const int v     = k * 256 + threadIdx.x;  // [0, 2048)
        const int pl    = v >> 10;                // 0 or 1: which plane
        const int h     = (v >> 4) & 63;          // row
        const int w4    = (v & 15) << 2;          // starting col of vector
        const int sh    = h  - off_y;
        const int sw    = w4 - off_x;
        r[k] = (f32x4){0.f, 0.f, 0.f, 0.f};
        if ((unsigned)sh < (unsigned)H_ && (unsigned)sw < (unsigned)W_) {
            r[k] = __builtin_nontemporal_load(&src[(pl << 10) + (sh << 4) + (sw >> 2)]);
        }
    }
    #pragma unroll
    for (int k = 0; k < 8; ++k) {
        __builtin_nontemporal_store(r[k], &dst[k * 256 + threadIdx.x]);
    }
}

extern "C" void kernel_launch(void* const* d_in, const int* in_sizes, int n_in,
                              void* d_out, int out_size, void* d_ws, size_t ws_size,
                              hipStream_t stream)
{
    const float* inp  = (const float*)d_in[0];
    const int*   offs = (const int*)d_in[1];
    float*       out  = (float*)d_out;

    dim3 grid(B_ * C_ / 2);   // 2304 blocks, two (b,c) planes each
    dim3 block(256);
    displace_kernel<<<grid, block, 0, stream>>>(inp, offs, out);
}

// Round 6
// 124.025 us; speedup vs baseline: 1.1080x; 1.1080x over previous
//
#include <hip/hip_runtime.h>

// DisplaceChannel: out[b,p,c,h,w] = in[b,p,c, h-off_y[p], w-off_x[p]] (0 if OOB)
// B=16, P=9, C/P=32 (C=288), H=W=64. Offsets are multiples of 32 -> 16B
// vectors stay aligned; validity is uniform within each vector.
//
// Simplest max-TLP structure: one (b,c) plane per 1024-thread block, one
// 16B vector per thread (1 load -> 1 store dependency chain). Traffic is at
// the floor: ~75.5 MB write + <=33.5 MB read (input likely L3-resident
// after the harness restore copy).

#define B_   16
#define C_   288
#define H_   64
#define W_   64

typedef float f32x4 __attribute__((ext_vector_type(4)));

__global__ __launch_bounds__(1024) void displace_kernel(
    const float* __restrict__ inp,
    const int*   __restrict__ offs,
    float*       __restrict__ out)
{
    const int bc = blockIdx.x;            // [0, B_*C_) -- one (b,c) plane
    const int c  = bc % C_;               // block-uniform
    const int p  = c >> 5;                // CHAN_PER_POS = 32
    const int off_x = offs[2 * p];
    const int off_y = offs[2 * p + 1];

    const f32x4* __restrict__ src = (const f32x4*)(inp + (size_t)bc * (H_ * W_));
    f32x4* __restrict__ dst       = (f32x4*)(out + (size_t)bc * (H_ * W_));

    const int v  = threadIdx.x;           // [0, 1024) -- one vector per thread
    const int h  = v >> 4;                // row
    const int w4 = (v & 15) << 2;         // starting col of this vector
    const int sh = h  - off_y;
    const int sw = w4 - off_x;

    f32x4 r = (f32x4){0.f, 0.f, 0.f, 0.f};
    if ((unsigned)sh < (unsigned)H_ && (unsigned)sw < (unsigned)W_) {
        r = __builtin_nontemporal_load(&src[(sh << 4) + (sw >> 2)]);
    }
    __builtin_nontemporal_store(r, &dst[v]);
}

extern "C" void kernel_launch(void* const* d_in, const int* in_sizes, int n_in,
                              void* d_out, int out_size, void* d_ws, size_t ws_size,
                              hipStream_t stream)
{
    const float* inp  = (const float*)d_in[0];
    const int*   offs = (const int*)d_in[1];
    float*       out  = (float*)d_out;

    dim3 grid(B_ * C_);   // 4608 blocks, one (b,c) plane each
    dim3 block(1024);
    displace_kernel<<<grid, block, 0, stream>>>(inp, offs, out);
}